// Round 3
// baseline (500.378 us; speedup 1.0000x reference)
//
#include <hip/hip_runtime.h>

#define DIM 4096

typedef __bf16 bf16x8 __attribute__((ext_vector_type(8)));
typedef float floatx4 __attribute__((ext_vector_type(4)));

__device__ __forceinline__ void async_ld16(void* lds, const void* g) {
  __builtin_amdgcn_global_load_lds(
      (const __attribute__((address_space(1))) unsigned int*)g,
      (__attribute__((address_space(3))) unsigned int*)lds, 16, 0, 0);
}

// ---------------- kernel 1: fused build_small + build_k012 ----------------
__global__ void build_k(const float* __restrict__ c0, const float* __restrict__ c1,
                        const float* __restrict__ c2, const float* __restrict__ c3,
                        const float* __restrict__ c4,
                        float* __restrict__ K012, float* __restrict__ K34T) {
  const int bid = blockIdx.x, tid = threadIdx.x;
  if (bid < 512) {
    __shared__ float K01s[128];
    const int abc = bid >> 2;
    const int ab = abc >> 3, c = abc & 7;
    if (tid < 128) {
      const int a = ab >> 2, b = ab & 3;
      const int j = tid >> 4, vw = tid & 15, v = vw >> 2, w = vw & 3;
      float s = 0.f;
#pragma unroll
      for (int i = 0; i < 8; ++i)
        s += c0[a * 32 + i * 4 + v] * c1[b * 256 + i * 32 + j * 4 + w];
      K01s[tid] = s;
    }
    __syncthreads();
    const int t = bid * 256 + tid;
    const int vwx = t & 127, k = (t >> 7) & 7;
    const int vw = vwx >> 3, xx = vwx & 7;
    float s = 0.f;
#pragma unroll
    for (int j = 0; j < 8; ++j)
      s += K01s[j * 16 + vw] * c2[c * 512 + j * 64 + k * 8 + xx];
    K012[t] = s;
  } else {
    const int u = (bid - 512) * 256 + tid;
    const int yz = u & 31, kk = (u >> 5) & 7, de = u >> 8;
    const int d = de >> 2, e = de & 3, y = yz >> 2, z = yz & 3;
    float s = 0.f;
#pragma unroll
    for (int l = 0; l < 8; ++l)
      s += c3[d * 512 + kk * 64 + l * 8 + y] * c4[e * 32 + l * 4 + z];
    K34T[kk * 1024 + yz * 32 + de] = s;
  }
}

// ---------------- kernel 2: fused build_wt + x_to_bf16 ----------------
__global__ void build_wt_conv(const float* __restrict__ K012, const float* __restrict__ K34T,
                              __bf16* __restrict__ WT,
                              const float* __restrict__ X, __bf16* __restrict__ Xb) {
  const int bid = blockIdx.x, tid = threadIdx.x;
  if (bid < 8192) {
    const long t = (long)bid * 256 + tid;
    const long e8 = t * 8;
    const int in = (int)(e8 & 4095), o = (int)(e8 >> 12);
    const int de0 = in & 31, abc = in >> 5;
    const int yz = o & 31, vwx = o >> 5;
    const float* kp = K012 + abc * 1024 + vwx;
    const float* vp = K34T + yz * 32 + de0;
    float s[8] = {};
#pragma unroll
    for (int k = 0; k < 8; ++k) {
      const float a = kp[k * 128];
      const float4 v0 = *(const float4*)(vp + k * 1024);
      const float4 v1 = *(const float4*)(vp + k * 1024 + 4);
      s[0] += a * v0.x; s[1] += a * v0.y; s[2] += a * v0.z; s[3] += a * v0.w;
      s[4] += a * v1.x; s[5] += a * v1.y; s[6] += a * v1.z; s[7] += a * v1.w;
    }
    bf16x8 w;
#pragma unroll
    for (int d = 0; d < 8; ++d) w[d] = (__bf16)s[d];
    ((bf16x8*)WT)[t] = w;
  } else {
    const long t = (long)(bid - 8192) * 256 + tid;
    const float4 a = ((const float4*)X)[t * 2];
    const float4 b = ((const float4*)X)[t * 2 + 1];
    bf16x8 w;
    w[0] = (__bf16)a.x; w[1] = (__bf16)a.y; w[2] = (__bf16)a.z; w[3] = (__bf16)a.w;
    w[4] = (__bf16)b.x; w[5] = (__bf16)b.y; w[6] = (__bf16)b.z; w[7] = (__bf16)b.w;
    ((bf16x8*)Xb)[t] = w;
  }
}

// ---------------- GEMM: 256x256, BK=64, 8 waves, snake 8-phase (8/4/8/4 ds_reads) ----------------
// Phases per tile (quadrants snaked): q0:(A0,B0) q1:(A0,B1) q2:(A1,B1) q3:(A1,B0).
// Each phase freshly ds_reads exactly ONE operand subtile (A:8 or B:4 b128);
// q3 reads B0 of the NEXT tile (no fresh operand for its own MMA -> reads fully
// overlap its 16 MFMA). B regs ping-pong 2 slots: even tiles B0->bs1,B1->bs0;
// odd tiles B0->bs0,B1->bs1. A single set (read->use same phase; dead next-next).
// Stage pipeline: 1 half-tile (2 global_load_lds) per phase, depth 4 phases:
//   E.q0:Ah0^{E+1} E.q1:Bh1^{E+1} E.q2:Ah1^{E+1} E.q3:Bh0^{E+2}
//   O.q0:Ah0^{E+2} O.q1:Bh1^{E+2} O.q2:Ah1^{E+2} O.q3:Bh0^{E+3}
// vmcnt(6) before EVERY closing barrier retires exactly the half staged 4 phases
// ago (2 loads), which is the half read in the NEXT phase (publish-by-barrier).
// WAR: each slot's overwrite is >=3 fenced barriers after its last read's drain.
// No manual lgkmcnt: C-level ds_reads let the compiler emit exact counted waits;
// MFMA clusters split 8+8 with sched_barrier so half2's reads drain under half1.

#define SB0()  __builtin_amdgcn_sched_barrier(0)
#define BARO() do { __builtin_amdgcn_s_barrier(); SB0(); } while (0)
#define ENDPH() do { asm volatile("s_waitcnt vmcnt(6)" ::: "memory"); \
                     __builtin_amdgcn_s_barrier(); SB0(); } while (0)
#define P1() __builtin_amdgcn_s_setprio(1)
#define P0() __builtin_amdgcn_s_setprio(0)

#define STA(p, h, koff) do { \
  async_ld16(&As[p][(h) * 128][0] + ldsq[0], agp[0] + (h) * 524288 + (koff)); \
  async_ld16(&As[p][(h) * 128][0] + ldsq[1], agp[1] + (h) * 524288 + (koff)); } while (0)
#define STB(p, h, koff) do { \
  async_ld16(&Bs[p][(h) * 128][0] + ldsq[0], bgp[0] + (h) * 524288 + (koff)); \
  async_ld16(&Bs[p][(h) * 128][0] + ldsq[1], bgp[1] + (h) * 524288 + (koff)); } while (0)

// A subtile for quadrant mh, frags f0..f0+1 (4 ds_read_b128)
#define RDA2(p, mh, f0) do { \
  _Pragma("unroll") for (int fi = (f0); fi < (f0) + 2; ++fi) { \
    const int row = ((mh) * 8 + 2 * fi + wm) * 16 + lm; \
    _Pragma("unroll") for (int kh = 0; kh < 2; ++kh) \
      af[fi][kh] = *(const bf16x8*)&As[p][row][((kh * 4 + kq) ^ (row & 7)) * 8]; \
  } } while (0)
// B frag g=(nh*2+gi) into slot sl (2 ds_read_b128)
#define RDB1(p, nh, sl, gi) do { \
  const int row = (4 * ((nh) * 2 + (gi)) + wn) * 16 + lm; \
  _Pragma("unroll") for (int kh = 0; kh < 2; ++kh) \
    bs[sl][gi][kh] = *(const bf16x8*)&Bs[p][row][((kh * 4 + kq) ^ (row & 7)) * 8]; \
  } while (0)

#define MMA8F(sl, mh, nh, f0) do { \
  _Pragma("unroll") for (int fi = (f0); fi < (f0) + 2; ++fi) \
  _Pragma("unroll") for (int gi = 0; gi < 2; ++gi) \
  _Pragma("unroll") for (int kh = 0; kh < 2; ++kh) \
    acc[(mh) * 4 + fi][(nh) * 2 + gi] = __builtin_amdgcn_mfma_f32_16x16x32_bf16( \
        af[fi][kh], bs[sl][gi][kh], acc[(mh) * 4 + fi][(nh) * 2 + gi], 0, 0, 0); } while (0)
#define MMA8G(sl, mh, nh, gi) do { \
  _Pragma("unroll") for (int fi = 0; fi < 4; ++fi) \
  _Pragma("unroll") for (int kh = 0; kh < 2; ++kh) \
    acc[(mh) * 4 + fi][(nh) * 2 + (gi)] = __builtin_amdgcn_mfma_f32_16x16x32_bf16( \
        af[fi][kh], bs[sl][gi][kh], acc[(mh) * 4 + fi][(nh) * 2 + (gi)], 0, 0, 0); } while (0)
#define MMA16(sl, mh, nh) do { \
  _Pragma("unroll") for (int fi = 0; fi < 4; ++fi) \
  _Pragma("unroll") for (int gi = 0; gi < 2; ++gi) \
  _Pragma("unroll") for (int kh = 0; kh < 2; ++kh) \
    acc[(mh) * 4 + fi][(nh) * 2 + gi] = __builtin_amdgcn_mfma_f32_16x16x32_bf16( \
        af[fi][kh], bs[sl][gi][kh], acc[(mh) * 4 + fi][(nh) * 2 + gi], 0, 0, 0); } while (0)

__global__ __launch_bounds__(512, 2) void gemm_8ph(const __bf16* __restrict__ A,
                                                   const __bf16* __restrict__ WT,
                                                   const float* __restrict__ bias,
                                                   float* __restrict__ C) {
  __shared__ __bf16 As[2][256][64];
  __shared__ __bf16 Bs[2][256][64];

  const int tid = threadIdx.x;
  const int gb = (blockIdx.x & 7) * 64 + (blockIdx.x >> 3);
  const int m0 = (gb >> 4) * 256;
  const int n0 = (gb & 15) * 256;

  const int wave = tid >> 6, lane = tid & 63;
  const int wm = wave & 1, wn = wave >> 1;
  const int lm = lane & 15, kq = lane >> 4;

  floatx4 acc[8][4] = {};
  bf16x8 af[4][2], bs[2][2][2];

  const __bf16* agp[2];
  const __bf16* bgp[2];
  int ldsq[2];
#pragma unroll
  for (int j = 0; j < 2; ++j) {
    const int q = tid + j * 512;
    const int r = q >> 3, pc = q & 7;
    const int c = pc ^ (r & 7);
    ldsq[j] = q * 8;
    agp[j] = A + (long)(m0 + r) * DIM + c * 8;
    bgp[j] = WT + (long)(n0 + r) * DIM + c * 8;
  }

  // prologue: flat issue order Bh0^0, Ah0^0, Bh1^0, Ah1^0, Bh0^1 (10 loads);
  // vmcnt(6) retires Bh0^0+Ah0^0; barrier publishes; pre-read B0^0 -> bs1.
  STB(0, 0, 0); STA(0, 0, 0); STB(0, 1, 0); STA(0, 1, 0); STB(1, 0, 64);
  asm volatile("s_waitcnt vmcnt(6)" ::: "memory");
  __builtin_amdgcn_s_barrier();
  SB0();
  RDB1(0, 0, 1, 0); RDB1(0, 0, 1, 1);

#pragma unroll 1
  for (int it = 0; it < 32; ++it) {
    const int kE1 = (2 * it + 1) * 64;                    // tile 2it+1 (always real)
    int t2 = 2 * it + 2; if (t2 > 63) t2 = 63;
    int t3 = 2 * it + 3; if (t3 > 63) t3 = 63;
    const int k2 = t2 * 64, k3 = t3 * 64;

    // ---- even tile E=2it (buf0): B0 in bs1, B1 in bs0 ----
    RDA2(0, 0, 0); SB0(); RDA2(0, 0, 2); STA(1, 0, kE1);  // E.q0: fresh A0
    BARO(); P1(); MMA8F(1, 0, 0, 0); SB0(); MMA8F(1, 0, 0, 2); P0();
    ENDPH();

    RDB1(0, 1, 0, 0); SB0(); RDB1(0, 1, 0, 1); STB(1, 1, kE1);  // E.q1: fresh B1
    BARO(); P1(); MMA8G(0, 0, 1, 0); SB0(); MMA8G(0, 0, 1, 1); P0();
    ENDPH();

    RDA2(0, 1, 0); SB0(); RDA2(0, 1, 2); STA(1, 1, kE1);  // E.q2: fresh A1
    BARO(); P1(); MMA8F(0, 1, 1, 0); SB0(); MMA8F(0, 1, 1, 2); P0();
    ENDPH();

    RDB1(1, 0, 0, 0); SB0(); RDB1(1, 0, 0, 1); STB(0, 0, k2);  // E.q3: read B0^{E+1}
    BARO(); P1(); MMA16(1, 1, 0); P0();                         //       MMA uses B0^E
    ENDPH();

    // ---- odd tile O=2it+1 (buf1): B0 in bs0, B1 in bs1 ----
    RDA2(1, 0, 0); SB0(); RDA2(1, 0, 2); STA(0, 0, k2);   // O.q0: fresh A0
    BARO(); P1(); MMA8F(0, 0, 0, 0); SB0(); MMA8F(0, 0, 0, 2); P0();
    ENDPH();

    RDB1(1, 1, 1, 0); SB0(); RDB1(1, 1, 1, 1); STB(0, 1, k2);  // O.q1: fresh B1
    BARO(); P1(); MMA8G(1, 0, 1, 0); SB0(); MMA8G(1, 0, 1, 1); P0();
    ENDPH();

    RDA2(1, 1, 0); SB0(); RDA2(1, 1, 2); STA(0, 1, k2);   // O.q2: fresh A1
    BARO(); P1(); MMA8F(1, 1, 1, 0); SB0(); MMA8F(1, 1, 1, 2); P0();
    ENDPH();

    RDB1(0, 0, 1, 0); SB0(); RDB1(0, 0, 1, 1); STB(1, 0, k3);  // O.q3: read B0^{E+2}
    BARO(); P1(); MMA16(0, 1, 0); P0();                         //       MMA uses B0^O
    ENDPH();
  }

  float bv[4];
#pragma unroll
  for (int g = 0; g < 4; ++g) bv[g] = bias[n0 + (4 * g + wn) * 16 + lm];
#pragma unroll
  for (int f = 0; f < 8; ++f) {
    const long mr = m0 + (2 * f + wm) * 16 + kq * 4;
#pragma unroll
    for (int g = 0; g < 4; ++g) {
      float* cp = C + mr * DIM + n0 + (4 * g + wn) * 16 + lm;
      cp[0]       = acc[f][g][0] + bv[g];
      cp[DIM]     = acc[f][g][1] + bv[g];
      cp[2 * DIM] = acc[f][g][2] + bv[g];
      cp[3 * DIM] = acc[f][g][3] + bv[g];
    }
  }
}

// ---------------- Fallback GEMM (fp32 A fused conversion) — unchanged ----------------
__global__ __launch_bounds__(256) void gemm_xw(const float* __restrict__ X,
                                               const __bf16* __restrict__ WT,
                                               const float* __restrict__ bias,
                                               float* __restrict__ C) {
  __shared__ __bf16 Asf[128 * 40];
  __shared__ __bf16 Bsf[128 * 32];

  const int tid = threadIdx.x;
  const int n0 = (blockIdx.x & 31) * 128;
  const int m0 = (blockIdx.x >> 5) * 128;

  const int wave = tid >> 6, lane = tid & 63;
  const int wm = (wave >> 1) * 64, wn = (wave & 1) * 64;
  const int lm = lane & 15, kq = lane >> 4;

  floatx4 acc[4][4] = {};

  const int ar = tid >> 1;
  const int ac = (tid & 1) * 16;
  const float* xp = X + (long)(m0 + ar) * DIM + ac;
  __bf16* as_dst = &Asf[ar * 40 + ac];

  const int u0 = tid, u1 = 256 + tid;
  const int r0 = u0 >> 2, r1 = u1 >> 2;
  const int ch0 = (u0 & 3) ^ (r0 & 3), ch1 = (u1 & 3) ^ (r1 & 3);
  const __bf16* wp0 = WT + (long)(n0 + r0) * DIM + ch0 * 8;
  const __bf16* wp1 = WT + (long)(n0 + r1) * DIM + ch1 * 8;

  float4 a0 = *(const float4*)(xp);
  float4 a1 = *(const float4*)(xp + 4);
  float4 a2 = *(const float4*)(xp + 8);
  float4 a3 = *(const float4*)(xp + 12);

#pragma unroll 1
  for (int k0 = 0; k0 < DIM; k0 += 32) {
    async_ld16(&Bsf[u0 * 8], wp0 + k0);
    async_ld16(&Bsf[u1 * 8], wp1 + k0);

    bf16x8 w0, w1;
    w0[0] = (__bf16)a0.x; w0[1] = (__bf16)a0.y; w0[2] = (__bf16)a0.z; w0[3] = (__bf16)a0.w;
    w0[4] = (__bf16)a1.x; w0[5] = (__bf16)a1.y; w0[6] = (__bf16)a1.z; w0[7] = (__bf16)a1.w;
    w1[0] = (__bf16)a2.x; w1[1] = (__bf16)a2.y; w1[2] = (__bf16)a2.z; w1[3] = (__bf16)a2.w;
    w1[4] = (__bf16)a3.x; w1[5] = (__bf16)a3.y; w1[6] = (__bf16)a3.z; w1[7] = (__bf16)a3.w;
    *(bf16x8*)(as_dst) = w0;
    *(bf16x8*)(as_dst + 8) = w1;

    if (k0 + 32 < DIM) {
      a0 = *(const float4*)(xp + k0 + 32);
      a1 = *(const float4*)(xp + k0 + 36);
      a2 = *(const float4*)(xp + k0 + 40);
      a3 = *(const float4*)(xp + k0 + 44);
    }
    __syncthreads();

    bf16x8 afv[4], bfr[4];
#pragma unroll
    for (int mi = 0; mi < 4; ++mi)
      afv[mi] = *(const bf16x8*)&Asf[(wm + mi * 16 + lm) * 40 + kq * 8];
#pragma unroll
    for (int ni = 0; ni < 4; ++ni) {
      int rr = wn + ni * 16 + lm;
      bfr[ni] = *(const bf16x8*)&Bsf[rr * 32 + ((kq ^ (rr & 3)) * 8)];
    }
#pragma unroll
    for (int mi = 0; mi < 4; ++mi)
#pragma unroll
      for (int ni = 0; ni < 4; ++ni)
        acc[mi][ni] = __builtin_amdgcn_mfma_f32_16x16x32_bf16(afv[mi], bfr[ni], acc[mi][ni], 0, 0, 0);
    __syncthreads();
  }

  float bv[4];
#pragma unroll
  for (int ni = 0; ni < 4; ++ni) bv[ni] = bias[n0 + wn + ni * 16 + lm];
#pragma unroll
  for (int mi = 0; mi < 4; ++mi) {
    long mr = m0 + wm + mi * 16 + kq * 4;
#pragma unroll
    for (int ni = 0; ni < 4; ++ni) {
      float* cp = C + mr * DIM + (n0 + wn + ni * 16 + lm);
      cp[0]       = acc[mi][ni][0] + bv[ni];
      cp[DIM]     = acc[mi][ni][1] + bv[ni];
      cp[2 * DIM] = acc[mi][ni][2] + bv[ni];
      cp[3 * DIM] = acc[mi][ni][3] + bv[ni];
    }
  }
}

extern "C" void kernel_launch(void* const* d_in, const int* in_sizes, int n_in,
                              void* d_out, int out_size, void* d_ws, size_t ws_size,
                              hipStream_t stream) {
  const float* x    = (const float*)d_in[0];
  const float* c0   = (const float*)d_in[1];
  const float* c1   = (const float*)d_in[2];
  const float* c2   = (const float*)d_in[3];
  const float* c3   = (const float*)d_in[4];
  const float* c4   = (const float*)d_in[5];
  const float* bias = (const float*)d_in[6];
  float* out = (float*)d_out;

  const size_t XB_SZ = 67108864;    // 8192*4096 bf16
  const size_t WT_SZ = 33554432;    // 4096*4096 bf16
  const size_t K012_SZ = 524288;    // 128*8*128 fp32
  const size_t K34_SZ = 32768;      // 8*32*32 fp32
  char* ws = (char*)d_ws;

  if (ws_size >= XB_SZ + WT_SZ + K012_SZ + K34_SZ) {
    __bf16* Xb  = (__bf16*)ws;
    __bf16* WT  = (__bf16*)(ws + XB_SZ);
    float* K012 = (float*)(ws + XB_SZ + WT_SZ);
    float* K34T = (float*)(ws + XB_SZ + WT_SZ + K012_SZ);

    build_k<<<544, 256, 0, stream>>>(c0, c1, c2, c3, c4, K012, K34T);
    build_wt_conv<<<24576, 256, 0, stream>>>(K012, K34T, WT, x, Xb);
    gemm_8ph<<<512, 512, 0, stream>>>(Xb, WT, bias, out);
  } else {
    __bf16* WT  = (__bf16*)ws;
    float* K012 = (float*)(ws + WT_SZ);
    float* K34T = (float*)(ws + WT_SZ + K012_SZ);

    build_k<<<544, 256, 0, stream>>>(c0, c1, c2, c3, c4, K012, K34T);
    build_wt_conv<<<8192, 256, 0, stream>>>(K012, K34T, WT, x, (__bf16*)nullptr);
    gemm_xw<<<2048, 256, 0, stream>>>(x, WT, bias, out);
  }
}

// Round 4
// 491.677 us; speedup vs baseline: 1.0177x; 1.0177x over previous
//
#include <hip/hip_runtime.h>

#define DIM 4096

typedef __bf16 bf16x8 __attribute__((ext_vector_type(8)));
typedef float floatx4 __attribute__((ext_vector_type(4)));

__device__ __forceinline__ void async_ld16(void* lds, const void* g) {
  __builtin_amdgcn_global_load_lds(
      (const __attribute__((address_space(1))) unsigned int*)g,
      (__attribute__((address_space(3))) unsigned int*)lds, 16, 0, 0);
}

// ---------------- kernel 1: fused build_small + build_k012 ----------------
__global__ void build_k(const float* __restrict__ c0, const float* __restrict__ c1,
                        const float* __restrict__ c2, const float* __restrict__ c3,
                        const float* __restrict__ c4,
                        float* __restrict__ K012, float* __restrict__ K34T) {
  const int bid = blockIdx.x, tid = threadIdx.x;
  if (bid < 512) {
    __shared__ float K01s[128];
    const int abc = bid >> 2;
    const int ab = abc >> 3, c = abc & 7;
    if (tid < 128) {
      const int a = ab >> 2, b = ab & 3;
      const int j = tid >> 4, vw = tid & 15, v = vw >> 2, w = vw & 3;
      float s = 0.f;
#pragma unroll
      for (int i = 0; i < 8; ++i)
        s += c0[a * 32 + i * 4 + v] * c1[b * 256 + i * 32 + j * 4 + w];
      K01s[tid] = s;
    }
    __syncthreads();
    const int t = bid * 256 + tid;
    const int vwx = t & 127, k = (t >> 7) & 7;
    const int vw = vwx >> 3, xx = vwx & 7;
    float s = 0.f;
#pragma unroll
    for (int j = 0; j < 8; ++j)
      s += K01s[j * 16 + vw] * c2[c * 512 + j * 64 + k * 8 + xx];
    K012[t] = s;
  } else {
    const int u = (bid - 512) * 256 + tid;
    const int yz = u & 31, kk = (u >> 5) & 7, de = u >> 8;
    const int d = de >> 2, e = de & 3, y = yz >> 2, z = yz & 3;
    float s = 0.f;
#pragma unroll
    for (int l = 0; l < 8; ++l)
      s += c3[d * 512 + kk * 64 + l * 8 + y] * c4[e * 32 + l * 4 + z];
    K34T[kk * 1024 + yz * 32 + de] = s;
  }
}

// ---------------- kernel 2: fused build_wt + x_to_bf16 ----------------
__global__ void build_wt_conv(const float* __restrict__ K012, const float* __restrict__ K34T,
                              __bf16* __restrict__ WT,
                              const float* __restrict__ X, __bf16* __restrict__ Xb) {
  const int bid = blockIdx.x, tid = threadIdx.x;
  if (bid < 8192) {
    const long t = (long)bid * 256 + tid;
    const long e8 = t * 8;
    const int in = (int)(e8 & 4095), o = (int)(e8 >> 12);
    const int de0 = in & 31, abc = in >> 5;
    const int yz = o & 31, vwx = o >> 5;
    const float* kp = K012 + abc * 1024 + vwx;
    const float* vp = K34T + yz * 32 + de0;
    float s[8] = {};
#pragma unroll
    for (int k = 0; k < 8; ++k) {
      const float a = kp[k * 128];
      const float4 v0 = *(const float4*)(vp + k * 1024);
      const float4 v1 = *(const float4*)(vp + k * 1024 + 4);
      s[0] += a * v0.x; s[1] += a * v0.y; s[2] += a * v0.z; s[3] += a * v0.w;
      s[4] += a * v1.x; s[5] += a * v1.y; s[6] += a * v1.z; s[7] += a * v1.w;
    }
    bf16x8 w;
#pragma unroll
    for (int d = 0; d < 8; ++d) w[d] = (__bf16)s[d];
    ((bf16x8*)WT)[t] = w;
  } else {
    const long t = (long)(bid - 8192) * 256 + tid;
    const float4 a = ((const float4*)X)[t * 2];
    const float4 b = ((const float4*)X)[t * 2 + 1];
    bf16x8 w;
    w[0] = (__bf16)a.x; w[1] = (__bf16)a.y; w[2] = (__bf16)a.z; w[3] = (__bf16)a.w;
    w[4] = (__bf16)b.x; w[5] = (__bf16)b.y; w[6] = (__bf16)b.z; w[7] = (__bf16)b.w;
    ((bf16x8*)Xb)[t] = w;
  }
}

// ---------------- GEMM: 256x256, BK=64, 8 waves, snake 8-phase, m201 waits ----------------
// Quadrant order per tile: q0:(A0,B0) q1:(A0,B1) q2:(A1,B1) q3:(A1,B0).
// Fresh ds_reads per phase: 8/4/8/4 (A-subtile or B-frag); q3 pre-reads B0 of the
// NEXT tile (its own MMA reuses retained regs). B regs: 2 slots, s0/s1 as below.
// Stage mapping (each phase stages the slot read in the PREVIOUS phase):
//   p0:Bh0^{E+2}(b0) p1:Ah0^{E+2} p2:Bh1^{E+2} p3:Ah1^{E+2}
//   p4:Bh0^{E+3}(b1) p5:Ah0^{E+3} p6:Bh1^{E+3} p7:Ah1^{E+3}
// vmcnt(6) ONLY at p3/p7 end (m201 placement). Retire ledger:
//   p3-VM6 retires stages <= p0  -> covers reads at p4(A0',p5(B1'),p6(A1'),p7(B0'')
//   p7-VM6 retires stages <= p4  -> covers next-iter p0..p3 reads
//   (every read's stage is 4-7 phases before its covering VM6 -> deep latency hiding)
// WAR: every slot overwrite is issued exactly 1 fenced barrier after the slot's
// reads drained (phases with same-phase-consumed reads drain via lgkmcnt(0) before
// MMA; p3/p7's future-reads drain via lgkmcnt(0) AFTER the MMA cluster, overlapped).

#define SB0()  __builtin_amdgcn_sched_barrier(0)
#define LGKM0() asm volatile("s_waitcnt lgkmcnt(0)" ::: "memory")
#define VM6()  asm volatile("s_waitcnt vmcnt(6)" ::: "memory")
#define BAR()  __builtin_amdgcn_s_barrier()
#define P1() __builtin_amdgcn_s_setprio(1)
#define P0() __builtin_amdgcn_s_setprio(0)

#define STA(p, h, koff) do { \
  async_ld16(&As[p][(h) * 128][0] + ldsq[0], agp[0] + (h) * 524288 + (koff)); \
  async_ld16(&As[p][(h) * 128][0] + ldsq[1], agp[1] + (h) * 524288 + (koff)); } while (0)
#define STB(p, h, koff) do { \
  async_ld16(&Bs[p][(h) * 128][0] + ldsq[0], bgp[0] + (h) * 524288 + (koff)); \
  async_ld16(&Bs[p][(h) * 128][0] + ldsq[1], bgp[1] + (h) * 524288 + (koff)); } while (0)

// A subtile for half mh: frags 0..3 (8 ds_read_b128)
#define RDA(p, mh) do { \
  _Pragma("unroll") for (int fi = 0; fi < 4; ++fi) { \
    const int row = ((mh) * 8 + 2 * fi + wm) * 16 + lm; \
    _Pragma("unroll") for (int kh = 0; kh < 2; ++kh) \
      af[fi][kh] = *(const bf16x8*)&As[p][row][((kh * 4 + kq) ^ (row & 7)) * 8]; \
  } } while (0)
// B half nh into slot sl (4 ds_read_b128)
#define RDB(p, nh, sl) do { \
  _Pragma("unroll") for (int gi = 0; gi < 2; ++gi) { \
    const int row = (4 * ((nh) * 2 + gi) + wn) * 16 + lm; \
    _Pragma("unroll") for (int kh = 0; kh < 2; ++kh) \
      bs[sl][gi][kh] = *(const bf16x8*)&Bs[p][row][((kh * 4 + kq) ^ (row & 7)) * 8]; \
  } } while (0)

// one C-quadrant (mh,nh) x K=64: 16 MFMA
#define MMAQ(sl, mh, nh) do { \
  _Pragma("unroll") for (int fi = 0; fi < 4; ++fi) \
  _Pragma("unroll") for (int gi = 0; gi < 2; ++gi) \
  _Pragma("unroll") for (int kh = 0; kh < 2; ++kh) \
    acc[(mh) * 4 + fi][(nh) * 2 + gi] = __builtin_amdgcn_mfma_f32_16x16x32_bf16( \
        af[fi][kh], bs[sl][gi][kh], acc[(mh) * 4 + fi][(nh) * 2 + gi], 0, 0, 0); } while (0)

__global__ __launch_bounds__(512, 2) void gemm_8ph(const __bf16* __restrict__ A,
                                                   const __bf16* __restrict__ WT,
                                                   const float* __restrict__ bias,
                                                   float* __restrict__ C) {
  __shared__ __bf16 As[2][256][64];
  __shared__ __bf16 Bs[2][256][64];

  const int tid = threadIdx.x;
  const int gb = (blockIdx.x & 7) * 64 + (blockIdx.x >> 3);
  const int m0 = (gb >> 4) * 256;
  const int n0 = (gb & 15) * 256;

  const int wave = tid >> 6, lane = tid & 63;
  const int wm = wave & 1, wn = wave >> 1;
  const int lm = lane & 15, kq = lane >> 4;

  floatx4 acc[8][4] = {};
  bf16x8 af[4][2], bs[2][2][2];

  const __bf16* agp[2];
  const __bf16* bgp[2];
  int ldsq[2];
#pragma unroll
  for (int j = 0; j < 2; ++j) {
    const int q = tid + j * 512;
    const int r = q >> 3, pc = q & 7;
    const int c = pc ^ (r & 7);
    ldsq[j] = q * 8;
    agp[j] = A + (long)(m0 + r) * DIM + c * 8;
    bgp[j] = WT + (long)(n0 + r) * DIM + c * 8;
  }

  // prologue: issue 8 halves: [Bh0^0 Ah0^0 Bh1^0 Ah1^0 Bh0^1] (must land) +
  // [Ah0^1 Bh1^1 Ah1^1] (stay in flight). vmcnt(6) retires the first 5 exactly.
  STB(0, 0, 0); STA(0, 0, 0); STB(0, 1, 0); STA(0, 1, 0); STB(1, 0, 64);
  STA(1, 0, 64); STB(1, 1, 64); STA(1, 1, 64);
  VM6();
  BAR(); SB0();
  RDB(0, 0, 0);  // pre-read B0^0 -> s0

#pragma unroll 1
  for (int it = 0; it < 32; ++it) {
    int t2 = 2 * it + 2; if (t2 > 63) t2 = 63;
    int t3 = 2 * it + 3; if (t3 > 63) t3 = 63;
    const int k2 = t2 * 64, k3 = t3 * 64;

    // ---- even tile E=2it (buf0); B0^E in s0 ----
    RDA(0, 0); STB(0, 0, k2);                 // p0: read A0^E | stage Bh0^{E+2}
    BAR(); LGKM0(); SB0(); P1(); MMAQ(0, 0, 0); P0(); BAR(); SB0();

    RDB(0, 1, 1); STA(0, 0, k2);              // p1: read B1^E->s1 | stage Ah0^{E+2}
    BAR(); LGKM0(); SB0(); P1(); MMAQ(1, 0, 1); P0(); BAR(); SB0();

    RDA(0, 1); STB(0, 1, k2);                 // p2: read A1^E | stage Bh1^{E+2}
    BAR(); LGKM0(); SB0(); P1(); MMAQ(1, 1, 1); P0(); BAR(); SB0();

    RDB(1, 0, 1); STA(0, 1, k2);              // p3: pre-read B0^{E+1}->s1 | stage Ah1^{E+2}
    BAR(); SB0(); P1(); MMAQ(0, 1, 0); P0();  //     MMA uses retained A1^E x B0^E
    LGKM0();                                  //     drain pre-reads before closing barrier (WAR)
    VM6();                                    //     tile E+1 fully landed
    BAR(); SB0();

    // ---- odd tile O=E+1 (buf1); B0^{E+1} in s1 ----
    RDA(1, 0); STB(1, 0, k3);                 // p4: read A0^{E+1} | stage Bh0^{E+3}
    BAR(); LGKM0(); SB0(); P1(); MMAQ(1, 0, 0); P0(); BAR(); SB0();

    RDB(1, 1, 0); STA(1, 0, k3);              // p5: read B1^{E+1}->s0 | stage Ah0^{E+3}
    BAR(); LGKM0(); SB0(); P1(); MMAQ(0, 0, 1); P0(); BAR(); SB0();

    RDA(1, 1); STB(1, 1, k3);                 // p6: read A1^{E+1} | stage Bh1^{E+3}
    BAR(); LGKM0(); SB0(); P1(); MMAQ(0, 1, 1); P0(); BAR(); SB0();

    RDB(0, 0, 0); STA(1, 1, k3);              // p7: pre-read B0^{E+2}->s0 | stage Ah1^{E+3}
    BAR(); SB0(); P1(); MMAQ(1, 1, 0); P0();  //     MMA uses retained A1^{E+1} x B0^{E+1}
    LGKM0();
    VM6();                                    //     tile E+2 fully landed
    BAR(); SB0();
  }

  float bv[4];
#pragma unroll
  for (int g = 0; g < 4; ++g) bv[g] = bias[n0 + (4 * g + wn) * 16 + lm];
#pragma unroll
  for (int f = 0; f < 8; ++f) {
    const long mr = m0 + (2 * f + wm) * 16 + kq * 4;
#pragma unroll
    for (int g = 0; g < 4; ++g) {
      float* cp = C + mr * DIM + n0 + (4 * g + wn) * 16 + lm;
      cp[0]       = acc[f][g][0] + bv[g];
      cp[DIM]     = acc[f][g][1] + bv[g];
      cp[2 * DIM] = acc[f][g][2] + bv[g];
      cp[3 * DIM] = acc[f][g][3] + bv[g];
    }
  }
}

// ---------------- Fallback GEMM (fp32 A fused conversion) — unchanged ----------------
__global__ __launch_bounds__(256) void gemm_xw(const float* __restrict__ X,
                                               const __bf16* __restrict__ WT,
                                               const float* __restrict__ bias,
                                               float* __restrict__ C) {
  __shared__ __bf16 Asf[128 * 40];
  __shared__ __bf16 Bsf[128 * 32];

  const int tid = threadIdx.x;
  const int n0 = (blockIdx.x & 31) * 128;
  const int m0 = (blockIdx.x >> 5) * 128;

  const int wave = tid >> 6, lane = tid & 63;
  const int wm = (wave >> 1) * 64, wn = (wave & 1) * 64;
  const int lm = lane & 15, kq = lane >> 4;

  floatx4 acc[4][4] = {};

  const int ar = tid >> 1;
  const int ac = (tid & 1) * 16;
  const float* xp = X + (long)(m0 + ar) * DIM + ac;
  __bf16* as_dst = &Asf[ar * 40 + ac];

  const int u0 = tid, u1 = 256 + tid;
  const int r0 = u0 >> 2, r1 = u1 >> 2;
  const int ch0 = (u0 & 3) ^ (r0 & 3), ch1 = (u1 & 3) ^ (r1 & 3);
  const __bf16* wp0 = WT + (long)(n0 + r0) * DIM + ch0 * 8;
  const __bf16* wp1 = WT + (long)(n0 + r1) * DIM + ch1 * 8;

  float4 a0 = *(const float4*)(xp);
  float4 a1 = *(const float4*)(xp + 4);
  float4 a2 = *(const float4*)(xp + 8);
  float4 a3 = *(const float4*)(xp + 12);

#pragma unroll 1
  for (int k0 = 0; k0 < DIM; k0 += 32) {
    async_ld16(&Bsf[u0 * 8], wp0 + k0);
    async_ld16(&Bsf[u1 * 8], wp1 + k0);

    bf16x8 w0, w1;
    w0[0] = (__bf16)a0.x; w0[1] = (__bf16)a0.y; w0[2] = (__bf16)a0.z; w0[3] = (__bf16)a0.w;
    w0[4] = (__bf16)a1.x; w0[5] = (__bf16)a1.y; w0[6] = (__bf16)a1.z; w0[7] = (__bf16)a1.w;
    w1[0] = (__bf16)a2.x; w1[1] = (__bf16)a2.y; w1[2] = (__bf16)a2.z; w1[3] = (__bf16)a2.w;
    w1[4] = (__bf16)a3.x; w1[5] = (__bf16)a3.y; w1[6] = (__bf16)a3.z; w1[7] = (__bf16)a3.w;
    *(bf16x8*)(as_dst) = w0;
    *(bf16x8*)(as_dst + 8) = w1;

    if (k0 + 32 < DIM) {
      a0 = *(const float4*)(xp + k0 + 32);
      a1 = *(const float4*)(xp + k0 + 36);
      a2 = *(const float4*)(xp + k0 + 40);
      a3 = *(const float4*)(xp + k0 + 44);
    }
    __syncthreads();

    bf16x8 afv[4], bfr[4];
#pragma unroll
    for (int mi = 0; mi < 4; ++mi)
      afv[mi] = *(const bf16x8*)&Asf[(wm + mi * 16 + lm) * 40 + kq * 8];
#pragma unroll
    for (int ni = 0; ni < 4; ++ni) {
      int rr = wn + ni * 16 + lm;
      bfr[ni] = *(const bf16x8*)&Bsf[rr * 32 + ((kq ^ (rr & 3)) * 8)];
    }
#pragma unroll
    for (int mi = 0; mi < 4; ++mi)
#pragma unroll
      for (int ni = 0; ni < 4; ++ni)
        acc[mi][ni] = __builtin_amdgcn_mfma_f32_16x16x32_bf16(afv[mi], bfr[ni], acc[mi][ni], 0, 0, 0);
    __syncthreads();
  }

  float bv[4];
#pragma unroll
  for (int ni = 0; ni < 4; ++ni) bv[ni] = bias[n0 + wn + ni * 16 + lm];
#pragma unroll
  for (int mi = 0; mi < 4; ++mi) {
    long mr = m0 + wm + mi * 16 + kq * 4;
#pragma unroll
    for (int ni = 0; ni < 4; ++ni) {
      float* cp = C + mr * DIM + (n0 + wn + ni * 16 + lm);
      cp[0]       = acc[mi][ni][0] + bv[ni];
      cp[DIM]     = acc[mi][ni][1] + bv[ni];
      cp[2 * DIM] = acc[mi][ni][2] + bv[ni];
      cp[3 * DIM] = acc[mi][ni][3] + bv[ni];
    }
  }
}

extern "C" void kernel_launch(void* const* d_in, const int* in_sizes, int n_in,
                              void* d_out, int out_size, void* d_ws, size_t ws_size,
                              hipStream_t stream) {
  const float* x    = (const float*)d_in[0];
  const float* c0   = (const float*)d_in[1];
  const float* c1   = (const float*)d_in[2];
  const float* c2   = (const float*)d_in[3];
  const float* c3   = (const float*)d_in[4];
  const float* c4   = (const float*)d_in[5];
  const float* bias = (const float*)d_in[6];
  float* out = (float*)d_out;

  const size_t XB_SZ = 67108864;    // 8192*4096 bf16
  const size_t WT_SZ = 33554432;    // 4096*4096 bf16
  const size_t K012_SZ = 524288;    // 128*8*128 fp32
  const size_t K34_SZ = 32768;      // 8*32*32 fp32
  char* ws = (char*)d_ws;

  if (ws_size >= XB_SZ + WT_SZ + K012_SZ + K34_SZ) {
    __bf16* Xb  = (__bf16*)ws;
    __bf16* WT  = (__bf16*)(ws + XB_SZ);
    float* K012 = (float*)(ws + XB_SZ + WT_SZ);
    float* K34T = (float*)(ws + XB_SZ + WT_SZ + K012_SZ);

    build_k<<<544, 256, 0, stream>>>(c0, c1, c2, c3, c4, K012, K34T);
    build_wt_conv<<<24576, 256, 0, stream>>>(K012, K34T, WT, x, Xb);
    gemm_8ph<<<512, 512, 0, stream>>>(Xb, WT, bias, out);
  } else {
    __bf16* WT  = (__bf16*)ws;
    float* K012 = (float*)(ws + WT_SZ);
    float* K34T = (float*)(ws + WT_SZ + K012_SZ);

    build_k<<<544, 256, 0, stream>>>(c0, c1, c2, c3, c4, K012, K34T);
    build_wt_conv<<<8192, 256, 0, stream>>>(K012, K34T, WT, x, (__bf16*)nullptr);
    gemm_xw<<<2048, 256, 0, stream>>>(x, WT, bias, out);
  }
}

// Round 5
// 486.012 us; speedup vs baseline: 1.0296x; 1.0117x over previous
//
#include <hip/hip_runtime.h>

#define DIM 4096

typedef __bf16 bf16x8 __attribute__((ext_vector_type(8)));
typedef float floatx4 __attribute__((ext_vector_type(4)));

__device__ __forceinline__ void async_ld16(void* lds, const void* g) {
  __builtin_amdgcn_global_load_lds(
      (const __attribute__((address_space(1))) unsigned int*)g,
      (__attribute__((address_space(3))) unsigned int*)lds, 16, 0, 0);
}

// ---------------- kernel 1: fused build_small + build_k012 ----------------
__global__ void build_k(const float* __restrict__ c0, const float* __restrict__ c1,
                        const float* __restrict__ c2, const float* __restrict__ c3,
                        const float* __restrict__ c4,
                        float* __restrict__ K012, float* __restrict__ K34T) {
  const int bid = blockIdx.x, tid = threadIdx.x;
  if (bid < 512) {
    __shared__ float K01s[128];
    const int abc = bid >> 2;
    const int ab = abc >> 3, c = abc & 7;
    if (tid < 128) {
      const int a = ab >> 2, b = ab & 3;
      const int j = tid >> 4, vw = tid & 15, v = vw >> 2, w = vw & 3;
      float s = 0.f;
#pragma unroll
      for (int i = 0; i < 8; ++i)
        s += c0[a * 32 + i * 4 + v] * c1[b * 256 + i * 32 + j * 4 + w];
      K01s[tid] = s;
    }
    __syncthreads();
    const int t = bid * 256 + tid;
    const int vwx = t & 127, k = (t >> 7) & 7;
    const int vw = vwx >> 3, xx = vwx & 7;
    float s = 0.f;
#pragma unroll
    for (int j = 0; j < 8; ++j)
      s += K01s[j * 16 + vw] * c2[c * 512 + j * 64 + k * 8 + xx];
    K012[t] = s;
  } else {
    const int u = (bid - 512) * 256 + tid;
    const int yz = u & 31, kk = (u >> 5) & 7, de = u >> 8;
    const int d = de >> 2, e = de & 3, y = yz >> 2, z = yz & 3;
    float s = 0.f;
#pragma unroll
    for (int l = 0; l < 8; ++l)
      s += c3[d * 512 + kk * 64 + l * 8 + y] * c4[e * 32 + l * 4 + z];
    K34T[kk * 1024 + yz * 32 + de] = s;
  }
}

// ---------------- kernel 2: fused build_wt (LDS K-slice) + x_to_bf16 ----------------
// WT-half: per block, o = bid>>1 is CONSTANT -> the needed K012 slice is just
// 512 floats (64 abc x 8 k at fixed vwx). Stage it in LDS (2 loads/thread)
// instead of 8 x 4KB-strided gathers per thread (suspected latency sink).
__global__ void build_wt_conv(const float* __restrict__ K012, const float* __restrict__ K34T,
                              __bf16* __restrict__ WT,
                              const float* __restrict__ X, __bf16* __restrict__ Xb) {
  const int bid = blockIdx.x, tid = threadIdx.x;
  if (bid < 8192) {
    __shared__ float Ks[512];  // [abc'=64][k=8]
    const int o = bid >> 1;                 // e8>>12, constant per block
    const int vwx = o >> 5, yz = o & 31;
    const int abc0 = (bid & 1) * 64;
#pragma unroll
    for (int e = tid; e < 512; e += 256)
      Ks[e] = K012[(abc0 + (e >> 3)) * 1024 + (e & 7) * 128 + vwx];
    __syncthreads();

    const int in = (bid & 1) * 2048 + tid * 8;
    const int de0 = in & 31, abcl = (in >> 5) - abc0;
    const float* vp = K34T + yz * 32 + de0;
    float kk[8];
#pragma unroll
    for (int k = 0; k < 8; ++k) kk[k] = Ks[abcl * 8 + k];
    float s[8] = {};
#pragma unroll
    for (int k = 0; k < 8; ++k) {
      const float a = kk[k];
      const float4 v0 = *(const float4*)(vp + k * 1024);
      const float4 v1 = *(const float4*)(vp + k * 1024 + 4);
      s[0] += a * v0.x; s[1] += a * v0.y; s[2] += a * v0.z; s[3] += a * v0.w;
      s[4] += a * v1.x; s[5] += a * v1.y; s[6] += a * v1.z; s[7] += a * v1.w;
    }
    bf16x8 w;
#pragma unroll
    for (int d = 0; d < 8; ++d) w[d] = (__bf16)s[d];
    ((bf16x8*)WT)[(long)bid * 256 + tid] = w;
  } else {
    const long t = (long)(bid - 8192) * 256 + tid;
    const float4 a = ((const float4*)X)[t * 2];
    const float4 b = ((const float4*)X)[t * 2 + 1];
    bf16x8 w;
    w[0] = (__bf16)a.x; w[1] = (__bf16)a.y; w[2] = (__bf16)a.z; w[3] = (__bf16)a.w;
    w[4] = (__bf16)b.x; w[5] = (__bf16)b.y; w[6] = (__bf16)b.z; w[7] = (__bf16)b.w;
    ((bf16x8*)Xb)[t] = w;
  }
}

// ---------------- GEMM: 256x256, BK=64, 8 waves, retained-B 8-phase ----------------
// Quadrants: q0:(A0xB0) q1:(A0xB1) q2:(A1xB1) q3:(A1xB0). B slots STABLE per tile
// (s0=B0, s1=B1, both live all 4 phases) -> fresh reads 12/4/8/0; q3 is a pure-MMA
// phase (zero reads, no drain).
// LDS addresses: row base is always a multiple of 16 -> row&7 == lm&7 for EVERY
// fragment -> chunk pc = (kh*4+kq)^(lm&7) is per-thread constant. All ds_reads are
// base[kh] + compile-time immediate (zero per-phase VALU).
// Stage map (1 half/phase, slot staged exactly 1 fenced barrier after its reads):
//   p0:Ah1^{E+1} p1:Bh0^{E+2} p2:Ah0^{E+2} p3:Bh1^{E+2}
//   p4:Ah1^{E+2} p5:Bh0^{E+3} p6:Ah0^{E+3} p7:Bh1^{E+3}
// VM6 at p3/p7 only. Ledger: outstanding at p3-end = prev{p5,p6,p7}+{p0..p3} = 14
// -> drain to 6 retires Bh0/Ah0/Bh1(prev)+Ah1(p0) = tile E+1 complete before p4.
// At p7-end = {p1..p7} = 14 -> retires p1..p4 = tile E+2 complete before next p0.
// Prologue: tile0(4 halves)+tile1(Bh0,Ah0,Bh1) = 14 loads; VM6 retires tile0 (8).
// Tail stages (k2/k3 past K) read garbage that stays inside the workspace
// allocation (Xb overflow -> WT region; WT overflow -> K012 region) and is never
// consumed. WAR: every slot overwrite >=1 full barrier after that slot's reads
// drained (reads drain via lgkmcnt(0) before the phase's MMA).

#define SB0()  __builtin_amdgcn_sched_barrier(0)
#define LGKM0() asm volatile("s_waitcnt lgkmcnt(0)" ::: "memory")
#define VM6()  asm volatile("s_waitcnt vmcnt(6)" ::: "memory")
#define BAR()  __builtin_amdgcn_s_barrier()
#define P1() __builtin_amdgcn_s_setprio(1)
#define P0() __builtin_amdgcn_s_setprio(0)

#define STA(p, h, koff) do { \
  async_ld16(&As[p][(h) * 128][0] + ldsq[0], agp[0] + (h) * 524288 + (koff)); \
  async_ld16(&As[p][(h) * 128][0] + ldsq[1], agp[1] + (h) * 524288 + (koff)); } while (0)
#define STB(p, h, koff) do { \
  async_ld16(&Bs[p][(h) * 128][0] + ldsq[0], bgp[0] + (h) * 524288 + (koff)); \
  async_ld16(&Bs[p][(h) * 128][0] + ldsq[1], bgp[1] + (h) * 524288 + (koff)); } while (0)

// A subtile mh of buffer p: 8 ds_read_b128, all base+immediate
#define RDA(p, mh) do { \
  _Pragma("unroll") for (int fi = 0; fi < 4; ++fi) \
  _Pragma("unroll") for (int kh = 0; kh < 2; ++kh) \
    af[fi][kh] = *(const bf16x8*)(aB[kh] + (p) * 32768 + ((mh) * 8 + 2 * fi) * 2048); \
  } while (0)
// B half nh of buffer p into stable slot sl: 4 ds_read_b128
#define RDB(p, nh, sl) do { \
  _Pragma("unroll") for (int gi = 0; gi < 2; ++gi) \
  _Pragma("unroll") for (int kh = 0; kh < 2; ++kh) \
    bs[sl][gi][kh] = *(const bf16x8*)(bB[kh] + (p) * 32768 + ((nh) * 2 + gi) * 8192); \
  } while (0)

// one C-quadrant (mh,nh) x K=64: 16 MFMA
#define MMAQ(sl, mh, nh) do { \
  _Pragma("unroll") for (int fi = 0; fi < 4; ++fi) \
  _Pragma("unroll") for (int gi = 0; gi < 2; ++gi) \
  _Pragma("unroll") for (int kh = 0; kh < 2; ++kh) \
    acc[(mh) * 4 + fi][(nh) * 2 + gi] = __builtin_amdgcn_mfma_f32_16x16x32_bf16( \
        af[fi][kh], bs[sl][gi][kh], acc[(mh) * 4 + fi][(nh) * 2 + gi], 0, 0, 0); } while (0)

__global__ __launch_bounds__(512, 2) void gemm_8ph(const __bf16* __restrict__ A,
                                                   const __bf16* __restrict__ WT,
                                                   const float* __restrict__ bias,
                                                   float* __restrict__ C) {
  __shared__ __bf16 As[2][256][64];
  __shared__ __bf16 Bs[2][256][64];

  const int tid = threadIdx.x;
  const int gb = (blockIdx.x & 7) * 64 + (blockIdx.x >> 3);
  const int m0 = (gb >> 4) * 256;
  const int n0 = (gb & 15) * 256;

  const int wave = tid >> 6, lane = tid & 63;
  const int wm = wave & 1, wn = wave >> 1;
  const int lm = lane & 15, kq = lane >> 4;

  floatx4 acc[8][4] = {};
  bf16x8 af[4][2], bs[2][2][2];

  // per-thread constant LDS read bases (chunk swizzle pc depends only on lm&7, kq, kh)
  const char* aB[2];
  const char* bB[2];
#pragma unroll
  for (int k = 0; k < 2; ++k) {
    const int pcv = ((k * 4 + kq) ^ (lm & 7)) * 16;
    aB[k] = (const char*)As + (wm * 16 + lm) * 128 + pcv;
    bB[k] = (const char*)Bs + (wn * 16 + lm) * 128 + pcv;
  }

  const __bf16* agp[2];
  const __bf16* bgp[2];
  int ldsq[2];
#pragma unroll
  for (int j = 0; j < 2; ++j) {
    const int q = tid + j * 512;
    const int r = q >> 3, pc = q & 7;
    const int c = pc ^ (r & 7);
    ldsq[j] = q * 8;
    agp[j] = A + (long)(m0 + r) * DIM + c * 8;
    bgp[j] = WT + (long)(n0 + r) * DIM + c * 8;
  }

  // prologue: tile0 fully + tile1 {Bh0,Ah0,Bh1} = 14 loads; VM6 retires tile0
  STB(0, 0, 0); STA(0, 0, 0); STB(0, 1, 0); STA(0, 1, 0);
  STB(1, 0, 64); STA(1, 0, 64); STB(1, 1, 64);
  VM6();
  BAR(); SB0();

#pragma unroll 1
  for (int it = 0; it < 32; ++it) {
    const int k1 = (2 * it + 1) * 64;
    const int k2 = (2 * it + 2) * 64;  // last iter: overflow reads stay in workspace, never consumed
    const int k3 = (2 * it + 3) * 64;

    // ---- even tile E=2it (buf0) ----
    RDA(0, 0); RDB(0, 0, 0); STA(1, 1, k1);   // p0: A0,B0 (12 rd) | Ah1^{E+1}
    BAR(); LGKM0(); SB0(); P1(); MMAQ(0, 0, 0); P0(); BAR(); SB0();

    RDB(0, 1, 1); STB(0, 0, k2);              // p1: B1 (4 rd) | Bh0^{E+2}
    BAR(); LGKM0(); SB0(); P1(); MMAQ(1, 0, 1); P0(); BAR(); SB0();

    RDA(0, 1); STA(0, 0, k2);                 // p2: A1 (8 rd) | Ah0^{E+2}
    BAR(); LGKM0(); SB0(); P1(); MMAQ(1, 1, 1); P0(); BAR(); SB0();

    STB(0, 1, k2);                            // p3: pure MMA (0 rd) | Bh1^{E+2}
    BAR(); SB0(); P1(); MMAQ(0, 1, 0); P0();
    VM6();                                    //     tile E+1 fully landed
    BAR(); SB0();

    // ---- odd tile O=E+1 (buf1) ----
    RDA(1, 0); RDB(1, 0, 0); STA(0, 1, k2);   // p4: A0,B0 (12 rd) | Ah1^{E+2}
    BAR(); LGKM0(); SB0(); P1(); MMAQ(0, 0, 0); P0(); BAR(); SB0();

    RDB(1, 1, 1); STB(1, 0, k3);              // p5: B1 (4 rd) | Bh0^{E+3}
    BAR(); LGKM0(); SB0(); P1(); MMAQ(1, 0, 1); P0(); BAR(); SB0();

    RDA(1, 1); STA(1, 0, k3);                 // p6: A1 (8 rd) | Ah0^{E+3}
    BAR(); LGKM0(); SB0(); P1(); MMAQ(1, 1, 1); P0(); BAR(); SB0();

    STB(1, 1, k3);                            // p7: pure MMA (0 rd) | Bh1^{E+3}
    BAR(); SB0(); P1(); MMAQ(0, 1, 0); P0();
    VM6();                                    //     tile E+2 fully landed
    BAR(); SB0();
  }

  float bv[4];
#pragma unroll
  for (int g = 0; g < 4; ++g) bv[g] = bias[n0 + (4 * g + wn) * 16 + lm];
#pragma unroll
  for (int f = 0; f < 8; ++f) {
    const long mr = m0 + (2 * f + wm) * 16 + kq * 4;
#pragma unroll
    for (int g = 0; g < 4; ++g) {
      float* cp = C + mr * DIM + n0 + (4 * g + wn) * 16 + lm;
      cp[0]       = acc[f][g][0] + bv[g];
      cp[DIM]     = acc[f][g][1] + bv[g];
      cp[2 * DIM] = acc[f][g][2] + bv[g];
      cp[3 * DIM] = acc[f][g][3] + bv[g];
    }
  }
}

// ---------------- Fallback GEMM (fp32 A fused conversion) — unchanged ----------------
__global__ __launch_bounds__(256) void gemm_xw(const float* __restrict__ X,
                                               const __bf16* __restrict__ WT,
                                               const float* __restrict__ bias,
                                               float* __restrict__ C) {
  __shared__ __bf16 Asf[128 * 40];
  __shared__ __bf16 Bsf[128 * 32];

  const int tid = threadIdx.x;
  const int n0 = (blockIdx.x & 31) * 128;
  const int m0 = (blockIdx.x >> 5) * 128;

  const int wave = tid >> 6, lane = tid & 63;
  const int wm = (wave >> 1) * 64, wn = (wave & 1) * 64;
  const int lm = lane & 15, kq = lane >> 4;

  floatx4 acc[4][4] = {};

  const int ar = tid >> 1;
  const int ac = (tid & 1) * 16;
  const float* xp = X + (long)(m0 + ar) * DIM + ac;
  __bf16* as_dst = &Asf[ar * 40 + ac];

  const int u0 = tid, u1 = 256 + tid;
  const int r0 = u0 >> 2, r1 = u1 >> 2;
  const int ch0 = (u0 & 3) ^ (r0 & 3), ch1 = (u1 & 3) ^ (r1 & 3);
  const __bf16* wp0 = WT + (long)(n0 + r0) * DIM + ch0 * 8;
  const __bf16* wp1 = WT + (long)(n0 + r1) * DIM + ch1 * 8;

  float4 a0 = *(const float4*)(xp);
  float4 a1 = *(const float4*)(xp + 4);
  float4 a2 = *(const float4*)(xp + 8);
  float4 a3 = *(const float4*)(xp + 12);

#pragma unroll 1
  for (int k0 = 0; k0 < DIM; k0 += 32) {
    async_ld16(&Bsf[u0 * 8], wp0 + k0);
    async_ld16(&Bsf[u1 * 8], wp1 + k0);

    bf16x8 w0, w1;
    w0[0] = (__bf16)a0.x; w0[1] = (__bf16)a0.y; w0[2] = (__bf16)a0.z; w0[3] = (__bf16)a0.w;
    w0[4] = (__bf16)a1.x; w0[5] = (__bf16)a1.y; w0[6] = (__bf16)a1.z; w0[7] = (__bf16)a1.w;
    w1[0] = (__bf16)a2.x; w1[1] = (__bf16)a2.y; w1[2] = (__bf16)a2.z; w1[3] = (__bf16)a2.w;
    w1[4] = (__bf16)a3.x; w1[5] = (__bf16)a3.y; w1[6] = (__bf16)a3.z; w1[7] = (__bf16)a3.w;
    *(bf16x8*)(as_dst) = w0;
    *(bf16x8*)(as_dst + 8) = w1;

    if (k0 + 32 < DIM) {
      a0 = *(const float4*)(xp + k0 + 32);
      a1 = *(const float4*)(xp + k0 + 36);
      a2 = *(const float4*)(xp + k0 + 40);
      a3 = *(const float4*)(xp + k0 + 44);
    }
    __syncthreads();

    bf16x8 afv[4], bfr[4];
#pragma unroll
    for (int mi = 0; mi < 4; ++mi)
      afv[mi] = *(const bf16x8*)&Asf[(wm + mi * 16 + lm) * 40 + kq * 8];
#pragma unroll
    for (int ni = 0; ni < 4; ++ni) {
      int rr = wn + ni * 16 + lm;
      bfr[ni] = *(const bf16x8*)&Bsf[rr * 32 + ((kq ^ (rr & 3)) * 8)];
    }
#pragma unroll
    for (int mi = 0; mi < 4; ++mi)
#pragma unroll
      for (int ni = 0; ni < 4; ++ni)
        acc[mi][ni] = __builtin_amdgcn_mfma_f32_16x16x32_bf16(afv[mi], bfr[ni], acc[mi][ni], 0, 0, 0);
    __syncthreads();
  }

  float bv[4];
#pragma unroll
  for (int ni = 0; ni < 4; ++ni) bv[ni] = bias[n0 + wn + ni * 16 + lm];
#pragma unroll
  for (int mi = 0; mi < 4; ++mi) {
    long mr = m0 + wm + mi * 16 + kq * 4;
#pragma unroll
    for (int ni = 0; ni < 4; ++ni) {
      float* cp = C + mr * DIM + (n0 + wn + ni * 16 + lm);
      cp[0]       = acc[mi][ni][0] + bv[ni];
      cp[DIM]     = acc[mi][ni][1] + bv[ni];
      cp[2 * DIM] = acc[mi][ni][2] + bv[ni];
      cp[3 * DIM] = acc[mi][ni][3] + bv[ni];
    }
  }
}

extern "C" void kernel_launch(void* const* d_in, const int* in_sizes, int n_in,
                              void* d_out, int out_size, void* d_ws, size_t ws_size,
                              hipStream_t stream) {
  const float* x    = (const float*)d_in[0];
  const float* c0   = (const float*)d_in[1];
  const float* c1   = (const float*)d_in[2];
  const float* c2   = (const float*)d_in[3];
  const float* c3   = (const float*)d_in[4];
  const float* c4   = (const float*)d_in[5];
  const float* bias = (const float*)d_in[6];
  float* out = (float*)d_out;

  const size_t XB_SZ = 67108864;    // 8192*4096 bf16
  const size_t WT_SZ = 33554432;    // 4096*4096 bf16
  const size_t K012_SZ = 524288;    // 128*8*128 fp32
  const size_t K34_SZ = 32768;      // 8*32*32 fp32
  char* ws = (char*)d_ws;

  if (ws_size >= XB_SZ + WT_SZ + K012_SZ + K34_SZ) {
    __bf16* Xb  = (__bf16*)ws;
    __bf16* WT  = (__bf16*)(ws + XB_SZ);
    float* K012 = (float*)(ws + XB_SZ + WT_SZ);
    float* K34T = (float*)(ws + XB_SZ + WT_SZ + K012_SZ);

    build_k<<<544, 256, 0, stream>>>(c0, c1, c2, c3, c4, K012, K34T);
    build_wt_conv<<<24576, 256, 0, stream>>>(K012, K34T, WT, x, Xb);
    gemm_8ph<<<512, 512, 0, stream>>>(Xb, WT, bias, out);
  } else {
    __bf16* WT  = (__bf16*)ws;
    float* K012 = (float*)(ws + WT_SZ);
    float* K34T = (float*)(ws + WT_SZ + K012_SZ);

    build_k<<<544, 256, 0, stream>>>(c0, c1, c2, c3, c4, K012, K34T);
    build_wt_conv<<<8192, 256, 0, stream>>>(K012, K34T, WT, x, (__bf16*)nullptr);
    gemm_xw<<<2048, 256, 0, stream>>>(x, WT, bias, out);
  }
}

// Round 6
// 468.442 us; speedup vs baseline: 1.0682x; 1.0375x over previous
//
#include <hip/hip_runtime.h>

#define DIM 4096

typedef __bf16 bf16x8 __attribute__((ext_vector_type(8)));
typedef float floatx4 __attribute__((ext_vector_type(4)));

__device__ __forceinline__ void async_ld16(void* lds, const void* g) {
  __builtin_amdgcn_global_load_lds(
      (const __attribute__((address_space(1))) unsigned int*)g,
      (__attribute__((address_space(3))) unsigned int*)lds, 16, 0, 0);
}

// ---------------- kernel 1: fused build_small + build_k012 ----------------
__global__ void build_k(const float* __restrict__ c0, const float* __restrict__ c1,
                        const float* __restrict__ c2, const float* __restrict__ c3,
                        const float* __restrict__ c4,
                        float* __restrict__ K012, float* __restrict__ K34T) {
  const int bid = blockIdx.x, tid = threadIdx.x;
  if (bid < 512) {
    __shared__ float K01s[128];
    const int abc = bid >> 2;
    const int ab = abc >> 3, c = abc & 7;
    if (tid < 128) {
      const int a = ab >> 2, b = ab & 3;
      const int j = tid >> 4, vw = tid & 15, v = vw >> 2, w = vw & 3;
      float s = 0.f;
#pragma unroll
      for (int i = 0; i < 8; ++i)
        s += c0[a * 32 + i * 4 + v] * c1[b * 256 + i * 32 + j * 4 + w];
      K01s[tid] = s;
    }
    __syncthreads();
    const int t = bid * 256 + tid;
    const int vwx = t & 127, k = (t >> 7) & 7;
    const int vw = vwx >> 3, xx = vwx & 7;
    float s = 0.f;
#pragma unroll
    for (int j = 0; j < 8; ++j)
      s += K01s[j * 16 + vw] * c2[c * 512 + j * 64 + k * 8 + xx];
    K012[t] = s;
  } else {
    const int u = (bid - 512) * 256 + tid;
    const int yz = u & 31, kk = (u >> 5) & 7, de = u >> 8;
    const int d = de >> 2, e = de & 3, y = yz >> 2, z = yz & 3;
    float s = 0.f;
#pragma unroll
    for (int l = 0; l < 8; ++l)
      s += c3[d * 512 + kk * 64 + l * 8 + y] * c4[e * 32 + l * 4 + z];
    K34T[kk * 1024 + yz * 32 + de] = s;
  }
}

// ---------------- kernel 2: fused build_wt (LDS K-slice) + x_to_bf16 ----------------
__global__ void build_wt_conv(const float* __restrict__ K012, const float* __restrict__ K34T,
                              __bf16* __restrict__ WT,
                              const float* __restrict__ X, __bf16* __restrict__ Xb) {
  const int bid = blockIdx.x, tid = threadIdx.x;
  if (bid < 8192) {
    __shared__ float Ks[512];  // [abc'=64][k=8]
    const int o = bid >> 1;
    const int vwx = o >> 5, yz = o & 31;
    const int abc0 = (bid & 1) * 64;
#pragma unroll
    for (int e = tid; e < 512; e += 256)
      Ks[e] = K012[(abc0 + (e >> 3)) * 1024 + (e & 7) * 128 + vwx];
    __syncthreads();

    const int in = (bid & 1) * 2048 + tid * 8;
    const int de0 = in & 31, abcl = (in >> 5) - abc0;
    const float* vp = K34T + yz * 32 + de0;
    float kk[8];
#pragma unroll
    for (int k = 0; k < 8; ++k) kk[k] = Ks[abcl * 8 + k];
    float s[8] = {};
#pragma unroll
    for (int k = 0; k < 8; ++k) {
      const float a = kk[k];
      const float4 v0 = *(const float4*)(vp + k * 1024);
      const float4 v1 = *(const float4*)(vp + k * 1024 + 4);
      s[0] += a * v0.x; s[1] += a * v0.y; s[2] += a * v0.z; s[3] += a * v0.w;
      s[4] += a * v1.x; s[5] += a * v1.y; s[6] += a * v1.z; s[7] += a * v1.w;
    }
    bf16x8 w;
#pragma unroll
    for (int d = 0; d < 8; ++d) w[d] = (__bf16)s[d];
    ((bf16x8*)WT)[(long)bid * 256 + tid] = w;
  } else {
    const long t = (long)(bid - 8192) * 256 + tid;
    const float4 a = ((const float4*)X)[t * 2];
    const float4 b = ((const float4*)X)[t * 2 + 1];
    bf16x8 w;
    w[0] = (__bf16)a.x; w[1] = (__bf16)a.y; w[2] = (__bf16)a.z; w[3] = (__bf16)a.w;
    w[4] = (__bf16)b.x; w[5] = (__bf16)b.y; w[6] = (__bf16)b.z; w[7] = (__bf16)b.w;
    ((bf16x8*)Xb)[t] = w;
  }
}

// ---------------- GEMM: 256x256, BK=64, 8 waves, counted-wait interleaved 8-phase --------
// Quadrants: q0:(A0xB0) q1:(A0xB1) q2:(A1xB1) q3:(A1xB0); B slots stable per tile
// (s0=B0, s1=B1). Reads per phase 12/4/8/0, issued in CONSUMPTION order; MFMA split
// into blocks separated by sched_barrier(0) with NO manual lgkm: hipcc emits minimal
// counted lgkmcnt per block (m97-verified), so later blocks' reads drain UNDER earlier
// blocks' MFMA. ONE barrier per phase (mid-phase barrier removed):
//  - WAR: stage in phase p targets slot read in p-1; p-1 reads drain before p-1's
//    last MMA block (its counted lgkm(0)); closing BAR separates -> safe.
//  - RAW/publish: VM6 at p3/p7 only + closing BAR (ledger identical to r5):
//    p3-VM6 retires prev{p5,p6,p7}+p0 stages = tile E+1 complete before p4;
//    p7-VM6 retires p1..p4 stages = tile E+2 complete before next p0.
// Stage map unchanged: p0:Ah1^{E+1} p1:Bh0^{E+2} p2:Ah0^{E+2} p3:Bh1^{E+2}
//                      p4:Ah1^{E+2} p5:Bh0^{E+3} p6:Ah0^{E+3} p7:Bh1^{E+3}
// Tail overflow reads stay inside the workspace allocation, never consumed.

#define SB0()  __builtin_amdgcn_sched_barrier(0)
#define VM6()  asm volatile("s_waitcnt vmcnt(6)" ::: "memory")
#define BAR()  __builtin_amdgcn_s_barrier()
#define P1() __builtin_amdgcn_s_setprio(1)
#define P0() __builtin_amdgcn_s_setprio(0)

#define STA(p, h, koff) do { \
  async_ld16(&As[p][(h) * 128][0] + ldsq[0], agp[0] + (h) * 524288 + (koff)); \
  async_ld16(&As[p][(h) * 128][0] + ldsq[1], agp[1] + (h) * 524288 + (koff)); } while (0)
#define STB(p, h, koff) do { \
  async_ld16(&Bs[p][(h) * 128][0] + ldsq[0], bgp[0] + (h) * 524288 + (koff)); \
  async_ld16(&Bs[p][(h) * 128][0] + ldsq[1], bgp[1] + (h) * 524288 + (koff)); } while (0)

// one A fragment pair (af[fi][0..1]): 2 ds_read_b128, base+immediate
#define RDA1(p, mh, fi) do { \
  af[fi][0] = *(const bf16x8*)(aB[0] + (p) * 32768 + ((mh) * 8 + 2 * (fi)) * 2048); \
  af[fi][1] = *(const bf16x8*)(aB[1] + (p) * 32768 + ((mh) * 8 + 2 * (fi)) * 2048); \
  } while (0)
// one B fragment (bs[sl][gi][0..1]): 2 ds_read_b128
#define RDB1(p, nh, sl, gi) do { \
  bs[sl][gi][0] = *(const bf16x8*)(bB[0] + (p) * 32768 + (((nh) * 2 + (gi)) * 8192)); \
  bs[sl][gi][1] = *(const bf16x8*)(bB[1] + (p) * 32768 + (((nh) * 2 + (gi)) * 8192)); \
  } while (0)

// 4 MFMA: one A-fragment fi against both B-frags of slot sl
#define MMA4(sl, mh, nh, fi) do { \
  _Pragma("unroll") for (int gi = 0; gi < 2; ++gi) \
  _Pragma("unroll") for (int kh = 0; kh < 2; ++kh) \
    acc[(mh) * 4 + (fi)][(nh) * 2 + gi] = __builtin_amdgcn_mfma_f32_16x16x32_bf16( \
        af[fi][kh], bs[sl][gi][kh], acc[(mh) * 4 + (fi)][(nh) * 2 + gi], 0, 0, 0); } while (0)
// 8 MFMA: all A-fragments against B-frag gi of slot sl
#define MMA8(sl, mh, nh, gi) do { \
  _Pragma("unroll") for (int fi = 0; fi < 4; ++fi) \
  _Pragma("unroll") for (int kh = 0; kh < 2; ++kh) \
    acc[(mh) * 4 + fi][(nh) * 2 + (gi)] = __builtin_amdgcn_mfma_f32_16x16x32_bf16( \
        af[fi][kh], bs[sl][(gi)][kh], acc[(mh) * 4 + fi][(nh) * 2 + (gi)], 0, 0, 0); } while (0)
// full 16-MFMA quadrant (pure-MMA phases)
#define MMAQ(sl, mh, nh) do { \
  _Pragma("unroll") for (int fi = 0; fi < 4; ++fi) \
  _Pragma("unroll") for (int gi = 0; gi < 2; ++gi) \
  _Pragma("unroll") for (int kh = 0; kh < 2; ++kh) \
    acc[(mh) * 4 + fi][(nh) * 2 + gi] = __builtin_amdgcn_mfma_f32_16x16x32_bf16( \
        af[fi][kh], bs[sl][gi][kh], acc[(mh) * 4 + fi][(nh) * 2 + gi], 0, 0, 0); } while (0)

__global__ __launch_bounds__(512, 2) void gemm_8ph(const __bf16* __restrict__ A,
                                                   const __bf16* __restrict__ WT,
                                                   const float* __restrict__ bias,
                                                   float* __restrict__ C) {
  __shared__ __bf16 As[2][256][64];
  __shared__ __bf16 Bs[2][256][64];

  const int tid = threadIdx.x;
  const int gb = (blockIdx.x & 7) * 64 + (blockIdx.x >> 3);
  const int m0 = (gb >> 4) * 256;
  const int n0 = (gb & 15) * 256;

  const int wave = tid >> 6, lane = tid & 63;
  const int wm = wave & 1, wn = wave >> 1;
  const int lm = lane & 15, kq = lane >> 4;

  floatx4 acc[8][4] = {};
  bf16x8 af[4][2], bs[2][2][2];

  // per-thread constant LDS read bases (chunk pc depends only on lm&7, kq, kh)
  const char* aB[2];
  const char* bB[2];
#pragma unroll
  for (int k = 0; k < 2; ++k) {
    const int pcv = ((k * 4 + kq) ^ (lm & 7)) * 16;
    aB[k] = (const char*)As + (wm * 16 + lm) * 128 + pcv;
    bB[k] = (const char*)Bs + (wn * 16 + lm) * 128 + pcv;
  }

  const __bf16* agp[2];
  const __bf16* bgp[2];
  int ldsq[2];
#pragma unroll
  for (int j = 0; j < 2; ++j) {
    const int q = tid + j * 512;
    const int r = q >> 3, pc = q & 7;
    const int c = pc ^ (r & 7);
    ldsq[j] = q * 8;
    agp[j] = A + (long)(m0 + r) * DIM + c * 8;
    bgp[j] = WT + (long)(n0 + r) * DIM + c * 8;
  }

  // prologue: tile0 fully + tile1 {Bh0,Ah0,Bh1} = 14 loads; VM6 retires tile0 (8)
  STB(0, 0, 0); STA(0, 0, 0); STB(0, 1, 0); STA(0, 1, 0);
  STB(1, 0, 64); STA(1, 0, 64); STB(1, 1, 64);
  VM6();
  BAR(); SB0();

#pragma unroll 1
  for (int it = 0; it < 32; ++it) {
    const int k1 = (2 * it + 1) * 64;
    const int k2 = (2 * it + 2) * 64;  // tail: overflow stays in workspace, never consumed
    const int k3 = (2 * it + 3) * 64;

    // ---- even tile E=2it (buf0) ----
    // p0: reads B0(4)+A0(8) in consumption order | stage Ah1^{E+1}
    RDB1(0, 0, 0, 0); RDB1(0, 0, 0, 1);
    RDA1(0, 0, 0); RDA1(0, 0, 1); RDA1(0, 0, 2); RDA1(0, 0, 3);
    SB0(); STA(1, 1, k1); SB0();
    P1();
    MMA4(0, 0, 0, 0); SB0();
    MMA4(0, 0, 0, 1); SB0();
    MMA4(0, 0, 0, 2); SB0();
    MMA4(0, 0, 0, 3);
    P0();
    BAR(); SB0();

    // p1: reads B1(4) | stage Bh0^{E+2}
    RDB1(0, 1, 1, 0); RDB1(0, 1, 1, 1);
    SB0(); STB(0, 0, k2); SB0();
    P1();
    MMA8(1, 0, 1, 0); SB0();
    MMA8(1, 0, 1, 1);
    P0();
    BAR(); SB0();

    // p2: reads A1(8) | stage Ah0^{E+2}
    RDA1(0, 1, 0); RDA1(0, 1, 1); RDA1(0, 1, 2); RDA1(0, 1, 3);
    SB0(); STA(0, 0, k2); SB0();
    P1();
    MMA4(1, 1, 1, 0); SB0();
    MMA4(1, 1, 1, 1); SB0();
    MMA4(1, 1, 1, 2); SB0();
    MMA4(1, 1, 1, 3);
    P0();
    BAR(); SB0();

    // p3: pure MMA (A1 x B0 retained) | stage Bh1^{E+2} | VM6: tile E+1 landed
    STB(0, 1, k2); SB0();
    P1(); MMAQ(0, 1, 0); P0();
    VM6();
    BAR(); SB0();

    // ---- odd tile O=E+1 (buf1) ----
    RDB1(1, 0, 0, 0); RDB1(1, 0, 0, 1);
    RDA1(1, 0, 0); RDA1(1, 0, 1); RDA1(1, 0, 2); RDA1(1, 0, 3);
    SB0(); STA(0, 1, k2); SB0();
    P1();
    MMA4(0, 0, 0, 0); SB0();
    MMA4(0, 0, 0, 1); SB0();
    MMA4(0, 0, 0, 2); SB0();
    MMA4(0, 0, 0, 3);
    P0();
    BAR(); SB0();

    RDB1(1, 1, 1, 0); RDB1(1, 1, 1, 1);
    SB0(); STB(1, 0, k3); SB0();
    P1();
    MMA8(1, 0, 1, 0); SB0();
    MMA8(1, 0, 1, 1);
    P0();
    BAR(); SB0();

    RDA1(1, 1, 0); RDA1(1, 1, 1); RDA1(1, 1, 2); RDA1(1, 1, 3);
    SB0(); STA(1, 0, k3); SB0();
    P1();
    MMA4(1, 1, 1, 0); SB0();
    MMA4(1, 1, 1, 1); SB0();
    MMA4(1, 1, 1, 2); SB0();
    MMA4(1, 1, 1, 3);
    P0();
    BAR(); SB0();

    STB(1, 1, k3); SB0();
    P1(); MMAQ(0, 1, 0); P0();
    VM6();
    BAR(); SB0();
  }

  float bv[4];
#pragma unroll
  for (int g = 0; g < 4; ++g) bv[g] = bias[n0 + (4 * g + wn) * 16 + lm];
#pragma unroll
  for (int f = 0; f < 8; ++f) {
    const long mr = m0 + (2 * f + wm) * 16 + kq * 4;
#pragma unroll
    for (int g = 0; g < 4; ++g) {
      float* cp = C + mr * DIM + n0 + (4 * g + wn) * 16 + lm;
      cp[0]       = acc[f][g][0] + bv[g];
      cp[DIM]     = acc[f][g][1] + bv[g];
      cp[2 * DIM] = acc[f][g][2] + bv[g];
      cp[3 * DIM] = acc[f][g][3] + bv[g];
    }
  }
}

// ---------------- Fallback GEMM (fp32 A fused conversion) — unchanged ----------------
__global__ __launch_bounds__(256) void gemm_xw(const float* __restrict__ X,
                                               const __bf16* __restrict__ WT,
                                               const float* __restrict__ bias,
                                               float* __restrict__ C) {
  __shared__ __bf16 Asf[128 * 40];
  __shared__ __bf16 Bsf[128 * 32];

  const int tid = threadIdx.x;
  const int n0 = (blockIdx.x & 31) * 128;
  const int m0 = (blockIdx.x >> 5) * 128;

  const int wave = tid >> 6, lane = tid & 63;
  const int wm = (wave >> 1) * 64, wn = (wave & 1) * 64;
  const int lm = lane & 15, kq = lane >> 4;

  floatx4 acc[4][4] = {};

  const int ar = tid >> 1;
  const int ac = (tid & 1) * 16;
  const float* xp = X + (long)(m0 + ar) * DIM + ac;
  __bf16* as_dst = &Asf[ar * 40 + ac];

  const int u0 = tid, u1 = 256 + tid;
  const int r0 = u0 >> 2, r1 = u1 >> 2;
  const int ch0 = (u0 & 3) ^ (r0 & 3), ch1 = (u1 & 3) ^ (r1 & 3);
  const __bf16* wp0 = WT + (long)(n0 + r0) * DIM + ch0 * 8;
  const __bf16* wp1 = WT + (long)(n0 + r1) * DIM + ch1 * 8;

  float4 a0 = *(const float4*)(xp);
  float4 a1 = *(const float4*)(xp + 4);
  float4 a2 = *(const float4*)(xp + 8);
  float4 a3 = *(const float4*)(xp + 12);

#pragma unroll 1
  for (int k0 = 0; k0 < DIM; k0 += 32) {
    async_ld16(&Bsf[u0 * 8], wp0 + k0);
    async_ld16(&Bsf[u1 * 8], wp1 + k0);

    bf16x8 w0, w1;
    w0[0] = (__bf16)a0.x; w0[1] = (__bf16)a0.y; w0[2] = (__bf16)a0.z; w0[3] = (__bf16)a0.w;
    w0[4] = (__bf16)a1.x; w0[5] = (__bf16)a1.y; w0[6] = (__bf16)a1.z; w0[7] = (__bf16)a1.w;
    w1[0] = (__bf16)a2.x; w1[1] = (__bf16)a2.y; w1[2] = (__bf16)a2.z; w1[3] = (__bf16)a2.w;
    w1[4] = (__bf16)a3.x; w1[5] = (__bf16)a3.y; w1[6] = (__bf16)a3.z; w1[7] = (__bf16)a3.w;
    *(bf16x8*)(as_dst) = w0;
    *(bf16x8*)(as_dst + 8) = w1;

    if (k0 + 32 < DIM) {
      a0 = *(const float4*)(xp + k0 + 32);
      a1 = *(const float4*)(xp + k0 + 36);
      a2 = *(const float4*)(xp + k0 + 40);
      a3 = *(const float4*)(xp + k0 + 44);
    }
    __syncthreads();

    bf16x8 afv[4], bfr[4];
#pragma unroll
    for (int mi = 0; mi < 4; ++mi)
      afv[mi] = *(const bf16x8*)&Asf[(wm + mi * 16 + lm) * 40 + kq * 8];
#pragma unroll
    for (int ni = 0; ni < 4; ++ni) {
      int rr = wn + ni * 16 + lm;
      bfr[ni] = *(const bf16x8*)&Bsf[rr * 32 + ((kq ^ (rr & 3)) * 8)];
    }
#pragma unroll
    for (int mi = 0; mi < 4; ++mi)
#pragma unroll
      for (int ni = 0; ni < 4; ++ni)
        acc[mi][ni] = __builtin_amdgcn_mfma_f32_16x16x32_bf16(afv[mi], bfr[ni], acc[mi][ni], 0, 0, 0);
    __syncthreads();
  }

  float bv[4];
#pragma unroll
  for (int ni = 0; ni < 4; ++ni) bv[ni] = bias[n0 + wn + ni * 16 + lm];
#pragma unroll
  for (int mi = 0; mi < 4; ++mi) {
    long mr = m0 + wm + mi * 16 + kq * 4;
#pragma unroll
    for (int ni = 0; ni < 4; ++ni) {
      float* cp = C + mr * DIM + (n0 + wn + ni * 16 + lm);
      cp[0]       = acc[mi][ni][0] + bv[ni];
      cp[DIM]     = acc[mi][ni][1] + bv[ni];
      cp[2 * DIM] = acc[mi][ni][2] + bv[ni];
      cp[3 * DIM] = acc[mi][ni][3] + bv[ni];
    }
  }
}

extern "C" void kernel_launch(void* const* d_in, const int* in_sizes, int n_in,
                              void* d_out, int out_size, void* d_ws, size_t ws_size,
                              hipStream_t stream) {
  const float* x    = (const float*)d_in[0];
  const float* c0   = (const float*)d_in[1];
  const float* c1   = (const float*)d_in[2];
  const float* c2   = (const float*)d_in[3];
  const float* c3   = (const float*)d_in[4];
  const float* c4   = (const float*)d_in[5];
  const float* bias = (const float*)d_in[6];
  float* out = (float*)d_out;

  const size_t XB_SZ = 67108864;    // 8192*4096 bf16
  const size_t WT_SZ = 33554432;    // 4096*4096 bf16
  const size_t K012_SZ = 524288;    // 128*8*128 fp32
  const size_t K34_SZ = 32768;      // 8*32*32 fp32
  char* ws = (char*)d_ws;

  if (ws_size >= XB_SZ + WT_SZ + K012_SZ + K34_SZ) {
    __bf16* Xb  = (__bf16*)ws;
    __bf16* WT  = (__bf16*)(ws + XB_SZ);
    float* K012 = (float*)(ws + XB_SZ + WT_SZ);
    float* K34T = (float*)(ws + XB_SZ + WT_SZ + K012_SZ);

    build_k<<<544, 256, 0, stream>>>(c0, c1, c2, c3, c4, K012, K34T);
    build_wt_conv<<<24576, 256, 0, stream>>>(K012, K34T, WT, x, Xb);
    gemm_8ph<<<512, 512, 0, stream>>>(Xb, WT, bias, out);
  } else {
    __bf16* WT  = (__bf16*)ws;
    float* K012 = (float*)(ws + WT_SZ);
    float* K34T = (float*)(ws + WT_SZ + K012_SZ);

    build_k<<<544, 256, 0, stream>>>(c0, c1, c2, c3, c4, K012, K34T);
    build_wt_conv<<<8192, 256, 0, stream>>>(K012, K34T, WT, x, (__bf16*)nullptr);
    gemm_xw<<<2048, 256, 0, stream>>>(x, WT, bias, out);
  }
}